// Round 1
// baseline (531.938 us; speedup 1.0000x reference)
//
#include <hip/hip_runtime.h>
#include <hip/hip_cooperative_groups.h>
#include <stdint.h>

namespace cg = cooperative_groups;

// Problem constants
#define B_      4
#define C_      3
#define H_      1024
#define W_      1024
#define OH_     31          // (1024-64)/32 + 1
#define NHS_    64          // 16-row half-strips per image
#define NP_     3844        // B * OH * OH
#define NPOSPB_ 961         // OH*OH
#define NPPAD_  4096
#define EPS_    1e-5f

// ---------------- fused-kernel ws layout (float offsets) ----------------
#define TILE_PLANE 24576    // 12 bc * 64 hs * 32 tx
#define OFF_TILE  0         // 4 planes * 24576 = 98304
#define OFF_STATS 98304     // 128 (s1 sum[32], s1 sq[32], s2 sum[32], s2 sq[32])
#define OFF_Y2    98432     // 32 * 4096 = 131072
#define OFF_A     229504    // 3 * 3844
#define OFF_BV    241036    // 3 * 3844   (total 252568 floats ~= 1.01 MB)

// ---------------- legacy (fallback) extra offsets ----------------
#define OFF_MX_L  98432     // 3 * 3844
#define OFF_MY_L  109964    // 3 * 3844
#define OFF_Y1_L  121496    // 32 * 4096
#define OFF_Y2_L  252568    // 32 * 4096
#define OFF_A_L   383640    // 3 * 3844
#define OFF_BV_L  395172    // 3 * 3844

typedef float f4 __attribute__((ext_vector_type(4)));

// ============================================================================
// Fused single cooperative kernel: 768 blocks x 256 threads.
//  phase1 (all blocks): 16-row half-strip partials of g, s, g*s, g*g  (== old k1)
//  phase2 (blocks 0..15): window sums -> h -> conv1; y1 + mx/my stay in REGISTERS
//  phase3 (blocks 0..15): BN1+ReLU -> conv2 -> y2(ws) + stats2
//  phase4 (blocks 0..15): BN2+ReLU -> conv3 -> A, b
//  phase5 (all blocks): bilinear upsample + out = A*g + b, 16 rows/block (== old k5)
// grid.sync() between phases replaces 4 kernel launches + y1/mx/my round trips.
// __launch_bounds__(256,4): VGPR<=128 -> 4 blocks/CU capacity >= 3/CU needed
// for 768 co-resident blocks (LDS 5.5 KB/block is not limiting).
// ============================================================================
__global__ __launch_bounds__(256, 4) void fused_all(
        const float* __restrict__ g,
        const float* __restrict__ s,
        const float* __restrict__ w1f,
        const float* __restrict__ g1f,
        const float* __restrict__ b1f,
        const float* __restrict__ w2f,
        const float* __restrict__ g2f,
        const float* __restrict__ b2f,
        const float* __restrict__ w3f,
        float* __restrict__ ws,
        float* __restrict__ out) {
    cg::grid_group grid = cg::this_grid();
    __shared__ float w2s[1024];
    __shared__ float w1s[192];
    __shared__ float w3s[96];
    __shared__ float scs[32], shs[32];

    int blk = blockIdx.x;
    int t   = threadIdx.x;

    // ---------------- phase 1: tile partial sums ----------------
    {
        int bc = blk >> 6;        // 0..11
        int hs = blk & 63;        // half-strip (16 rows)
        const f4* gp = (const f4*)(g + ((size_t)bc * H_ + (size_t)hs * 16) * W_);
        const f4* sp = (const f4*)(s + ((size_t)bc * H_ + (size_t)hs * 16) * W_);
        float sg = 0.f, ss = 0.f, sgs = 0.f, sgg = 0.f;
#pragma unroll 4
        for (int r = 0; r < 16; r++) {
            f4 gv = gp[r * (W_ / 4) + t];
            f4 sv = __builtin_nontemporal_load(sp + r * (W_ / 4) + t);  // src read exactly once
            sg  += (gv.x + gv.y) + (gv.z + gv.w);
            ss  += (sv.x + sv.y) + (sv.z + sv.w);
            sgs += gv.x * sv.x + gv.y * sv.y + gv.z * sv.z + gv.w * sv.w;
            sgg += gv.x * gv.x + gv.y * gv.y + gv.z * gv.z + gv.w * gv.w;
        }
#pragma unroll
        for (int off = 4; off; off >>= 1) {
            sg  += __shfl_down(sg,  off, 8);
            ss  += __shfl_down(ss,  off, 8);
            sgs += __shfl_down(sgs, off, 8);
            sgg += __shfl_down(sgg, off, 8);
        }
        if ((t & 7) == 0) {
            int tx = t >> 3;
            int base = (bc * NHS_ + hs) * 32 + tx;
            ws[OFF_TILE + 0 * TILE_PLANE + base] = sg;
            ws[OFF_TILE + 1 * TILE_PLANE + base] = ss;
            ws[OFF_TILE + 2 * TILE_PLANE + base] = sgs;
            ws[OFF_TILE + 3 * TILE_PLANE + base] = sgg;
        }
        if (blk == 0 && t < 128) ws[OFF_STATS + t] = 0.f;   // zero stats accumulators
        if (blk < 16) {                                      // preload MLP weights to LDS
            for (int i = t; i < 1024; i += 256) w2s[i] = w2f[i];
            if (t < 192) w1s[t] = w1f[t];
            if (t < 96)  w3s[t] = w3f[t];
        }
    }
    grid.sync();

    // mid-phase per-thread state (position p lives in registers across syncs)
    int p = blk * 256 + t;
    bool ok = (blk < 16) && (p < NP_);
    float a[32];                       // y1, then z1 in place
    float mx0 = 0.f, mx1 = 0.f, mx2 = 0.f, my0 = 0.f, my1 = 0.f, my2 = 0.f;

    // ---------------- phase 2: box sums -> h -> conv1 (regs) + stats1 ----------------
    if (blk < 16) {
        int pp = ok ? p : 0;
        int b = pp / NPOSPB_;
        int r = pp % NPOSPB_;
        int oy = r / OH_, ox = r % OH_;
        float h[6], mxv[3], myv[3];
#pragma unroll
        for (int c = 0; c < C_; c++) {
            int bc = b * 3 + c;
            int base = (bc * NHS_ + oy * 2) * 32 + ox;
            float S[4];
#pragma unroll
            for (int pl = 0; pl < 4; pl++) {
                const float* tp = ws + OFF_TILE + pl * TILE_PLANE + base;
                S[pl] = ((tp[0]  + tp[1])  + (tp[32] + tp[33]))
                      + ((tp[64] + tp[65]) + (tp[96] + tp[97]));
            }
            const float inv = 1.f / 4096.f;
            float mx = S[0] * inv, my = S[1] * inv;
            h[c]     = S[2] * inv - mx * my;
            h[3 + c] = S[3] * inv - mx * mx;
            mxv[c] = mx; myv[c] = my;
        }
        mx0 = mxv[0]; mx1 = mxv[1]; mx2 = mxv[2];
        my0 = myv[0]; my1 = myv[1]; my2 = myv[2];
#pragma unroll
        for (int o = 0; o < 32; o++) {
            float y = 0.f;
#pragma unroll
            for (int i = 0; i < 6; i++) y += w1s[o * 6 + i] * h[i];
            a[o] = y;
            float yv = ok ? y : 0.f;
            float sv = yv, sq = yv * yv;
#pragma unroll
            for (int off = 32; off; off >>= 1) {
                sv += __shfl_down(sv, off, 64);
                sq += __shfl_down(sq, off, 64);
            }
            if ((t & 63) == 0) {
                atomicAdd(&ws[OFF_STATS + o], sv);
                atomicAdd(&ws[OFF_STATS + 32 + o], sq);
            }
        }
    }
    grid.sync();

    // ---------------- phase 3: BN1+ReLU -> conv2 -> y2(ws) + stats2 ----------------
    if (blk < 16) {
        if (t < 32) {
            float m = ws[OFF_STATS + t] * (1.f / NP_);
            float v = ws[OFF_STATS + 32 + t] * (1.f / NP_) - m * m;
            float scale = g1f[t] * rsqrtf(v + EPS_);
            scs[t] = scale; shs[t] = b1f[t] - m * scale;
        }
        __syncthreads();
#pragma unroll
        for (int i = 0; i < 32; i++) a[i] = fmaxf(a[i] * scs[i] + shs[i], 0.f);
#pragma unroll
        for (int o = 0; o < 32; o++) {
            float y = 0.f;
#pragma unroll
            for (int i = 0; i < 32; i++) y += w2s[o * 32 + i] * a[i];
            ws[OFF_Y2 + o * NPPAD_ + p] = y;   // unguarded: p<4096 in-bounds, pad holds finite junk (never poison)
            float yv = ok ? y : 0.f;
            float sv = yv, sq = yv * yv;
#pragma unroll
            for (int off = 32; off; off >>= 1) {
                sv += __shfl_down(sv, off, 64);
                sq += __shfl_down(sq, off, 64);
            }
            if ((t & 63) == 0) {
                atomicAdd(&ws[OFF_STATS + 64 + o], sv);
                atomicAdd(&ws[OFF_STATS + 96 + o], sq);
            }
        }
    }
    grid.sync();

    // ---------------- phase 4: BN2+ReLU -> conv3 -> A, b ----------------
    if (blk < 16) {
        if (t < 32) {
            float m = ws[OFF_STATS + 64 + t] * (1.f / NP_);
            float v = ws[OFF_STATS + 96 + t] * (1.f / NP_) - m * m;
            float scale = g2f[t] * rsqrtf(v + EPS_);
            scs[t] = scale; shs[t] = b2f[t] - m * scale;
        }
        __syncthreads();
        float z[32];
#pragma unroll
        for (int i = 0; i < 32; i++) {
            float y = ws[OFF_Y2 + i * NPPAD_ + p];
            z[i] = fmaxf(y * scs[i] + shs[i], 0.f);
        }
        if (ok) {
#pragma unroll
            for (int c = 0; c < 3; c++) {
                float av = 0.f;
#pragma unroll
                for (int i = 0; i < 32; i++) av += w3s[c * 32 + i] * z[i];
                float mx = (c == 0) ? mx0 : ((c == 1) ? mx1 : mx2);
                float my = (c == 0) ? my0 : ((c == 1) ? my1 : my2);
                ws[OFF_A  + c * NP_ + p] = av;
                ws[OFF_BV + c * NP_ + p] = my - av * mx;
            }
        }
    }
    grid.sync();

    // ---------------- phase 5: bilinear upsample + out = A*g + b (16 rows/block) ----------------
    {
        int row0 = blk * 16;              // 768 blocks * 16 = 12288 = B*C*H rows
        int bc = row0 >> 10;              // uniform per block (16 | 1024)
        int b5 = bc / 3, c5 = bc % 3;
        const float* Abase = ws + OFF_A  + c5 * NP_ + b5 * NPOSPB_;
        const float* Bbase = ws + OFF_BV + c5 * NP_ + b5 * NPOSPB_;
        // x-direction weights are row-invariant: hoist out of the row loop
        int x0_[4], x1_[4]; float wx_[4];
#pragma unroll
        for (int j = 0; j < 4; j++) {
            int x = t * 4 + j;
            float fx = (float)x * (30.f / 1023.f);
            int x0 = (int)fx;
            wx_[j] = fx - (float)x0;
            x0_[j] = x0;
            x1_[j] = min(x0 + 1, 30);
        }
        for (int rr = 0; rr < 16; rr++) {
            int y = (row0 & 1023) + rr;
            float fy = (float)y * (30.f / 1023.f);
            int y0 = (int)fy;
            float wy = fy - (float)y0;
            int y1i = min(y0 + 1, 30);
            const float* A0 = Abase + y0  * OH_;
            const float* A1 = Abase + y1i * OH_;
            const float* B0 = Bbase + y0  * OH_;
            const float* B1 = Bbase + y1i * OH_;
            size_t rowoff = ((size_t)bc * H_ + (size_t)y) * W_;
            f4 gv = ((const f4*)(g + rowoff))[t];
            float go[4] = { gv.x, gv.y, gv.z, gv.w };
            float r[4];
#pragma unroll
            for (int j = 0; j < 4; j++) {
                int x0 = x0_[j], x1 = x1_[j];
                float wx = wx_[j];
                float av = (A0[x0] * (1.f - wx) + A0[x1] * wx) * (1.f - wy)
                         + (A1[x0] * (1.f - wx) + A1[x1] * wx) * wy;
                float bb = (B0[x0] * (1.f - wx) + B0[x1] * wx) * (1.f - wy)
                         + (B1[x0] * (1.f - wx) + B1[x1] * wx) * wy;
                r[j] = av * go[j] + bb;
            }
            f4 ov; ov.x = r[0]; ov.y = r[1]; ov.z = r[2]; ov.w = r[3];
            __builtin_nontemporal_store(ov, (f4*)(out + rowoff) + t);   // out never re-read
        }
    }
}

// ============================================================================
// Fallback path (verbatim previous 5-kernel pipeline) in case cooperative
// launch is rejected under graph capture.
// ============================================================================
__global__ __launch_bounds__(256) void k1_tilesums(
        const float* __restrict__ g,
        const float* __restrict__ s,
        float* __restrict__ ws) {
    int blk = blockIdx.x;
    int bc = blk >> 6;
    int hs = blk & 63;
    int t  = threadIdx.x;
    const f4* gp = (const f4*)(g + ((size_t)bc * H_ + (size_t)hs * 16) * W_);
    const f4* sp = (const f4*)(s + ((size_t)bc * H_ + (size_t)hs * 16) * W_);
    float sg = 0.f, ss = 0.f, sgs = 0.f, sgg = 0.f;
#pragma unroll 4
    for (int r = 0; r < 16; r++) {
        f4 gv = gp[r * (W_ / 4) + t];
        f4 sv = __builtin_nontemporal_load(sp + r * (W_ / 4) + t);
        sg  += (gv.x + gv.y) + (gv.z + gv.w);
        ss  += (sv.x + sv.y) + (sv.z + sv.w);
        sgs += gv.x * sv.x + gv.y * sv.y + gv.z * sv.z + gv.w * sv.w;
        sgg += gv.x * gv.x + gv.y * gv.y + gv.z * gv.z + gv.w * gv.w;
    }
#pragma unroll
    for (int off = 4; off; off >>= 1) {
        sg  += __shfl_down(sg,  off, 8);
        ss  += __shfl_down(ss,  off, 8);
        sgs += __shfl_down(sgs, off, 8);
        sgg += __shfl_down(sgg, off, 8);
    }
    if ((t & 7) == 0) {
        int tx = t >> 3;
        int base = (bc * NHS_ + hs) * 32 + tx;
        ws[OFF_TILE + 0 * TILE_PLANE + base] = sg;
        ws[OFF_TILE + 1 * TILE_PLANE + base] = ss;
        ws[OFF_TILE + 2 * TILE_PLANE + base] = sgs;
        ws[OFF_TILE + 3 * TILE_PLANE + base] = sgg;
    }
    if (blk == 0 && t < 128) ws[OFF_STATS + t] = 0.f;
}

__global__ __launch_bounds__(256) void k2_conv1(
        const float* __restrict__ w1f,
        float* __restrict__ ws) {
    __shared__ float w[192];
    int t = threadIdx.x;
    if (t < 192) w[t] = w1f[t];
    __syncthreads();
    int p = blockIdx.x * 256 + t;
    bool ok = p < NP_;
    int pp = ok ? p : 0;
    int b = pp / NPOSPB_;
    int r = pp % NPOSPB_;
    int oy = r / OH_, ox = r % OH_;
    float h[6];
#pragma unroll
    for (int c = 0; c < C_; c++) {
        int bc = b * 3 + c;
        int base = (bc * NHS_ + oy * 2) * 32 + ox;
        float S[4];
#pragma unroll
        for (int pl = 0; pl < 4; pl++) {
            const float* tp = ws + OFF_TILE + pl * TILE_PLANE + base;
            S[pl] = ((tp[0]  + tp[1])  + (tp[32] + tp[33]))
                  + ((tp[64] + tp[65]) + (tp[96] + tp[97]));
        }
        const float inv = 1.f / 4096.f;
        float mx = S[0] * inv, my = S[1] * inv;
        float cov = S[2] * inv - mx * my;
        float var = S[3] * inv - mx * mx;
        h[c] = cov; h[3 + c] = var;
        if (ok) { ws[OFF_MX_L + c * NP_ + pp] = mx; ws[OFF_MY_L + c * NP_ + pp] = my; }
    }
#pragma unroll
    for (int o = 0; o < 32; o++) {
        float y = 0.f;
#pragma unroll
        for (int i = 0; i < 6; i++) y += w[o * 6 + i] * h[i];
        if (ok) ws[OFF_Y1_L + o * NPPAD_ + pp] = y;
        float yv = ok ? y : 0.f;
        float sv = yv, sq = yv * yv;
#pragma unroll
        for (int off = 32; off; off >>= 1) {
            sv += __shfl_down(sv, off, 64);
            sq += __shfl_down(sq, off, 64);
        }
        if ((t & 63) == 0) {
            atomicAdd(&ws[OFF_STATS + o], sv);
            atomicAdd(&ws[OFF_STATS + 32 + o], sq);
        }
    }
}

__global__ __launch_bounds__(256) void k3_conv2(
        const float* __restrict__ w2f,
        const float* __restrict__ g1f,
        const float* __restrict__ b1f,
        float* __restrict__ ws) {
    __shared__ float w[1024];
    __shared__ float sc[32], sh[32];
    int t = threadIdx.x;
    for (int i = t; i < 1024; i += 256) w[i] = w2f[i];
    if (t < 32) {
        float m = ws[OFF_STATS + t] * (1.f / NP_);
        float v = ws[OFF_STATS + 32 + t] * (1.f / NP_) - m * m;
        float scale = g1f[t] * rsqrtf(v + EPS_);
        sc[t] = scale; sh[t] = b1f[t] - m * scale;
    }
    __syncthreads();
    int p = blockIdx.x * 256 + t;
    bool ok = p < NP_;
    float z[32];
#pragma unroll
    for (int i = 0; i < 32; i++) {
        float y = ws[OFF_Y1_L + i * NPPAD_ + p];
        z[i] = fmaxf(y * sc[i] + sh[i], 0.f);
    }
#pragma unroll
    for (int o = 0; o < 32; o++) {
        float y = 0.f;
#pragma unroll
        for (int i = 0; i < 32; i++) y += w[o * 32 + i] * z[i];
        if (ok) ws[OFF_Y2_L + o * NPPAD_ + p] = y;
        float yv = ok ? y : 0.f;
        float sv = yv, sq = yv * yv;
#pragma unroll
        for (int off = 32; off; off >>= 1) {
            sv += __shfl_down(sv, off, 64);
            sq += __shfl_down(sq, off, 64);
        }
        if ((t & 63) == 0) {
            atomicAdd(&ws[OFF_STATS + 64 + o], sv);
            atomicAdd(&ws[OFF_STATS + 96 + o], sq);
        }
    }
}

__global__ __launch_bounds__(256) void k4_conv3(
        const float* __restrict__ w3f,
        const float* __restrict__ g2f,
        const float* __restrict__ b2f,
        float* __restrict__ ws) {
    __shared__ float w[96];
    __shared__ float sc[32], sh[32];
    int t = threadIdx.x;
    if (t < 96) w[t] = w3f[t];
    if (t >= 128 && t < 160) {
        int o = t - 128;
        float m = ws[OFF_STATS + 64 + o] * (1.f / NP_);
        float v = ws[OFF_STATS + 96 + o] * (1.f / NP_) - m * m;
        float scale = g2f[o] * rsqrtf(v + EPS_);
        sc[o] = scale; sh[o] = b2f[o] - m * scale;
    }
    __syncthreads();
    int p = blockIdx.x * 256 + t;
    if (p >= NP_) return;
    float z[32];
#pragma unroll
    for (int i = 0; i < 32; i++) {
        float y = ws[OFF_Y2_L + i * NPPAD_ + p];
        z[i] = fmaxf(y * sc[i] + sh[i], 0.f);
    }
#pragma unroll
    for (int c = 0; c < 3; c++) {
        float a = 0.f;
#pragma unroll
        for (int i = 0; i < 32; i++) a += w[c * 32 + i] * z[i];
        float mx = ws[OFF_MX_L + c * NP_ + p];
        float my = ws[OFF_MY_L + c * NP_ + p];
        ws[OFF_A_L  + c * NP_ + p] = a;
        ws[OFF_BV_L + c * NP_ + p] = my - a * mx;
    }
}

__global__ __launch_bounds__(256) void k5_final(
        const float* __restrict__ g,
        const float* __restrict__ ws,
        float* __restrict__ out) {
    int blk = blockIdx.x;
    int y  = blk & 1023;
    int bc = blk >> 10;
    int b = bc / 3, c = bc % 3;
    float fy = (float)y * (30.f / 1023.f);
    int y0 = (int)fy;
    float wy = fy - (float)y0;
    int y1i = min(y0 + 1, 30);
    const float* A0 = ws + OFF_A_L  + c * NP_ + b * NPOSPB_ + y0  * OH_;
    const float* A1 = ws + OFF_A_L  + c * NP_ + b * NPOSPB_ + y1i * OH_;
    const float* B0 = ws + OFF_BV_L + c * NP_ + b * NPOSPB_ + y0  * OH_;
    const float* B1 = ws + OFF_BV_L + c * NP_ + b * NPOSPB_ + y1i * OH_;
    int t = threadIdx.x;
    size_t rowoff = ((size_t)bc * H_ + (size_t)y) * W_;
    const f4* gp = (const f4*)(g + rowoff);
    f4* op = (f4*)(out + rowoff);
    f4 gv = gp[t];
    float go[4] = { gv.x, gv.y, gv.z, gv.w };
    float r[4];
#pragma unroll
    for (int j = 0; j < 4; j++) {
        int x = t * 4 + j;
        float fx = (float)x * (30.f / 1023.f);
        int x0 = (int)fx;
        float wx = fx - (float)x0;
        int x1 = min(x0 + 1, 30);
        float a  = (A0[x0] * (1.f - wx) + A0[x1] * wx) * (1.f - wy)
                 + (A1[x0] * (1.f - wx) + A1[x1] * wx) * wy;
        float bb = (B0[x0] * (1.f - wx) + B0[x1] * wx) * (1.f - wy)
                 + (B1[x0] * (1.f - wx) + B1[x1] * wx) * wy;
        r[j] = a * go[j] + bb;
    }
    f4 ov;
    ov.x = r[0]; ov.y = r[1]; ov.z = r[2]; ov.w = r[3];
    __builtin_nontemporal_store(ov, op + t);
}

extern "C" void kernel_launch(void* const* d_in, const int* in_sizes, int n_in,
                              void* d_out, int out_size, void* d_ws, size_t ws_size,
                              hipStream_t stream) {
    const float* guide = (const float*)d_in[0];
    const float* src   = (const float*)d_in[1];
    // d_in[2] = box_w (all ones) -- unused; N == 4096 everywhere (VALID padding)
    const float* w1 = (const float*)d_in[3];
    const float* g1 = (const float*)d_in[4];
    const float* b1 = (const float*)d_in[5];
    const float* w2 = (const float*)d_in[6];
    const float* g2 = (const float*)d_in[7];
    const float* b2 = (const float*)d_in[8];
    const float* w3 = (const float*)d_in[9];
    float* ws = (float*)d_ws;
    float* out = (float*)d_out;

    void* args[] = { (void*)&guide, (void*)&src,
                     (void*)&w1, (void*)&g1, (void*)&b1,
                     (void*)&w2, (void*)&g2, (void*)&b2, (void*)&w3,
                     (void*)&ws, (void*)&out };
    hipError_t e = hipLaunchCooperativeKernel((const void*)fused_all,
                                              dim3(768), dim3(256), args, 0, stream);
    if (e != hipSuccess) {
        // Fallback: previous 5-kernel pipeline
        hipLaunchKernelGGL(k1_tilesums, dim3(B_ * C_ * NHS_), dim3(256), 0, stream, guide, src, ws);
        hipLaunchKernelGGL(k2_conv1,   dim3(16),              dim3(256), 0, stream, w1, ws);
        hipLaunchKernelGGL(k3_conv2,   dim3(16),              dim3(256), 0, stream, w2, g1, b1, ws);
        hipLaunchKernelGGL(k4_conv3,   dim3(16),              dim3(256), 0, stream, w3, g2, b2, ws);
        hipLaunchKernelGGL(k5_final,   dim3(B_ * C_ * H_),    dim3(256), 0, stream, guide, ws, out);
    }
}

// Round 2
// 309.456 us; speedup vs baseline: 1.7189x; 1.7189x over previous
//
#include <hip/hip_runtime.h>
#include <stdint.h>

// Problem constants
#define B_      4
#define C_      3
#define H_      1024
#define W_      1024
#define OH_     31          // (1024-64)/32 + 1
#define NHS_    64          // 16-row half-strips per image
#define NP_     3844        // B * OH * OH
#define NPOSPB_ 961         // OH*OH
#define EPS_    1e-5f

// ---------------- ws layout (float offsets) ----------------
#define TILE_PLANE 24576    // 12 bc * 64 hs * 32 tx
#define OFF_TILE  0         // 4 planes * 24576 = 98304
#define OFF_MX    98304     // 3 * 3844
#define OFF_MY    109836    // 3 * 3844
#define OFF_Y1    121368    // position-major [4096][32] = 131072
#define OFF_Y2    252440    // position-major [4096][32] = 131072
#define OFF_A     383512    // 3 * 3844
#define OFF_BV    395044    // 3 * 3844  (total 406576 floats ~= 1.63 MB)

typedef float f4 __attribute__((ext_vector_type(4)));

// ---------------- K1: 16-row half-strip partial sums of g, s, g*s, g*g per 32-col tile ----------------
// grid = (B*C)*64 = 768 blocks, 256 threads. Block = (bc, 16-row half-strip). (proven round-0)
__global__ __launch_bounds__(256) void k1_tilesums(
        const float* __restrict__ g,
        const float* __restrict__ s,
        float* __restrict__ ws) {
    int blk = blockIdx.x;
    int bc = blk >> 6;        // 0..11
    int hs = blk & 63;        // half-strip (16 rows)
    int t  = threadIdx.x;     // covers columns [4t, 4t+4)
    const f4* gp = (const f4*)(g + ((size_t)bc * H_ + (size_t)hs * 16) * W_);
    const f4* sp = (const f4*)(s + ((size_t)bc * H_ + (size_t)hs * 16) * W_);
    float sg = 0.f, ss = 0.f, sgs = 0.f, sgg = 0.f;
#pragma unroll 4
    for (int r = 0; r < 16; r++) {
        f4 gv = gp[r * (W_ / 4) + t];
        f4 sv = __builtin_nontemporal_load(sp + r * (W_ / 4) + t);  // src read exactly once
        sg  += (gv.x + gv.y) + (gv.z + gv.w);
        ss  += (sv.x + sv.y) + (sv.z + sv.w);
        sgs += gv.x * sv.x + gv.y * sv.y + gv.z * sv.z + gv.w * sv.w;
        sgg += gv.x * gv.x + gv.y * gv.y + gv.z * gv.z + gv.w * gv.w;
    }
    // reduce groups of 8 lanes (8 threads * 4 cols = 32 cols = one tileX)
#pragma unroll
    for (int off = 4; off; off >>= 1) {
        sg  += __shfl_down(sg,  off, 8);
        ss  += __shfl_down(ss,  off, 8);
        sgs += __shfl_down(sgs, off, 8);
        sgg += __shfl_down(sgg, off, 8);
    }
    if ((t & 7) == 0) {
        int tx = t >> 3;
        int base = (bc * NHS_ + hs) * 32 + tx;
        ws[OFF_TILE + 0 * TILE_PLANE + base] = sg;
        ws[OFF_TILE + 1 * TILE_PLANE + base] = ss;
        ws[OFF_TILE + 2 * TILE_PLANE + base] = sgs;
        ws[OFF_TILE + 3 * TILE_PLANE + base] = sgg;
    }
}

// ============================================================================
// KMID: single workgroup (1 block x 512 threads) fusing old k2+k3+k4.
// BN batch stats via __syncthreads-based block reduction — no grid barriers,
// no cross-kernel atomic round trips, no dispatch-order assumptions.
// Each thread owns positions p = t + it*512, it = 0..7 (4096 >= NP=3844).
// w1/w2/w3 are read with wave-uniform compile-time offsets from GLOBAL memory
// -> compiler emits s_load into SGPRs (scalar pipe, overlaps the VALU FMA
// stream). Do NOT stage them in LDS: 1024 uniform ds_reads per position would
// serialize on the LDS pipe (~12 cyc/b128) and dominate the kernel.
// ============================================================================
__global__ __launch_bounds__(512, 2) void kmid(
        const float* __restrict__ w1f,
        const float* __restrict__ g1f,
        const float* __restrict__ b1f,
        const float* __restrict__ w2f,
        const float* __restrict__ g2f,
        const float* __restrict__ b2f,
        const float* __restrict__ w3f,
        float* __restrict__ ws) {
    __shared__ float red[8][64];        // per-wave reduction buffer (sum[32] | sumsq[32])
    __shared__ float scs[32], shs[32];  // BN scale/shift broadcast
    int t  = threadIdx.x;
    int wv = t >> 6, ln = t & 63;

    // ---------------- phase A: h -> conv1 -> y1(ws) + mx/my(ws) + stats1 ----------------
    float s1[32], q1[32];
#pragma unroll
    for (int o = 0; o < 32; o++) { s1[o] = 0.f; q1[o] = 0.f; }
#pragma unroll 1
    for (int it = 0; it < 8; it++) {
        int p = t + it * 512;
        if (p < NP_) {
            int b = p / NPOSPB_;
            int r = p % NPOSPB_;
            int oy = r / OH_, ox = r % OH_;
            float h[6];
#pragma unroll
            for (int c = 0; c < 3; c++) {
                int bc = b * 3 + c;
                int base = (bc * NHS_ + oy * 2) * 32 + ox;
                float S[4];
#pragma unroll
                for (int pl = 0; pl < 4; pl++) {
                    const float* tp = ws + OFF_TILE + pl * TILE_PLANE + base;
                    S[pl] = ((tp[0]  + tp[1])  + (tp[32] + tp[33]))
                          + ((tp[64] + tp[65]) + (tp[96] + tp[97]));
                }
                const float inv = 1.f / 4096.f;
                float mx = S[0] * inv, my = S[1] * inv;
                h[c]     = S[2] * inv - mx * my;
                h[3 + c] = S[3] * inv - mx * mx;
                ws[OFF_MX + c * NP_ + p] = mx;
                ws[OFF_MY + c * NP_ + p] = my;
            }
            float* y1p = ws + OFF_Y1 + (size_t)p * 32;
#pragma unroll
            for (int o = 0; o < 32; o++) {
                float y = 0.f;
#pragma unroll
                for (int i = 0; i < 6; i++) y += w1f[o * 6 + i] * h[i];
                y1p[o] = y;
                s1[o] += y; q1[o] += y * y;
            }
        }
    }
    // block reduction: wave shuffle -> LDS -> totals -> BN1 params
#pragma unroll
    for (int o = 0; o < 32; o++) {
#pragma unroll
        for (int off = 32; off; off >>= 1) {
            s1[o] += __shfl_down(s1[o], off, 64);
            q1[o] += __shfl_down(q1[o], off, 64);
        }
    }
    if (ln == 0) {
#pragma unroll
        for (int o = 0; o < 32; o++) { red[wv][o] = s1[o]; red[wv][32 + o] = q1[o]; }
    }
    __syncthreads();
    if (t < 64) {
        float tot = red[0][t] + red[1][t] + red[2][t] + red[3][t]
                  + red[4][t] + red[5][t] + red[6][t] + red[7][t];
        red[0][t] = tot;          // column-private: no race
    }
    __syncthreads();
    if (t < 32) {
        float m = red[0][t] * (1.f / NP_);
        float v = red[0][32 + t] * (1.f / NP_) - m * m;
        float sc = g1f[t] * rsqrtf(v + EPS_);
        scs[t] = sc; shs[t] = b1f[t] - m * sc;
    }
    __syncthreads();
    float sc_r[32], sh_r[32];
#pragma unroll
    for (int i = 0; i < 32; i++) { sc_r[i] = scs[i]; sh_r[i] = shs[i]; }

    // ---------------- phase B: BN1+ReLU -> conv2 -> y2(ws) + stats2 ----------------
    float s2[32], q2[32];
#pragma unroll
    for (int o = 0; o < 32; o++) { s2[o] = 0.f; q2[o] = 0.f; }
#pragma unroll 1
    for (int it = 0; it < 8; it++) {
        int p = t + it * 512;
        if (p < NP_) {
            const float* y1p = ws + OFF_Y1 + (size_t)p * 32;
            float z[32];
#pragma unroll
            for (int i = 0; i < 32; i++)
                z[i] = fmaxf(y1p[i] * sc_r[i] + sh_r[i], 0.f);
            float* y2p = ws + OFF_Y2 + (size_t)p * 32;
#pragma unroll
            for (int o = 0; o < 32; o++) {
                float y = 0.f;
#pragma unroll
                for (int i = 0; i < 32; i++) y += w2f[o * 32 + i] * z[i];  // SGPR operand
                y2p[o] = y;
                s2[o] += y; q2[o] += y * y;
            }
        }
    }
#pragma unroll
    for (int o = 0; o < 32; o++) {
#pragma unroll
        for (int off = 32; off; off >>= 1) {
            s2[o] += __shfl_down(s2[o], off, 64);
            q2[o] += __shfl_down(q2[o], off, 64);
        }
    }
    __syncthreads();                    // ensure phase-A reads of red are done
    if (ln == 0) {
#pragma unroll
        for (int o = 0; o < 32; o++) { red[wv][o] = s2[o]; red[wv][32 + o] = q2[o]; }
    }
    __syncthreads();
    if (t < 64) {
        float tot = red[0][t] + red[1][t] + red[2][t] + red[3][t]
                  + red[4][t] + red[5][t] + red[6][t] + red[7][t];
        red[0][t] = tot;
    }
    __syncthreads();
    if (t < 32) {
        float m = red[0][t] * (1.f / NP_);
        float v = red[0][32 + t] * (1.f / NP_) - m * m;
        float sc = g2f[t] * rsqrtf(v + EPS_);
        scs[t] = sc; shs[t] = b2f[t] - m * sc;
    }
    __syncthreads();
#pragma unroll
    for (int i = 0; i < 32; i++) { sc_r[i] = scs[i]; sh_r[i] = shs[i]; }

    // ---------------- phase C: BN2+ReLU -> conv3 -> A, b ----------------
#pragma unroll 1
    for (int it = 0; it < 8; it++) {
        int p = t + it * 512;
        if (p < NP_) {
            const float* y2p = ws + OFF_Y2 + (size_t)p * 32;
            float z[32];
#pragma unroll
            for (int i = 0; i < 32; i++)
                z[i] = fmaxf(y2p[i] * sc_r[i] + sh_r[i], 0.f);
#pragma unroll
            for (int c = 0; c < 3; c++) {
                float a = 0.f;
#pragma unroll
                for (int i = 0; i < 32; i++) a += w3f[c * 32 + i] * z[i];
                float mx = ws[OFF_MX + c * NP_ + p];
                float my = ws[OFF_MY + c * NP_ + p];
                ws[OFF_A  + c * NP_ + p] = a;
                ws[OFF_BV + c * NP_ + p] = my - a * mx;
            }
        }
    }
}

// ---------------- K5: bilinear upsample (align_corners) + out = A*g + b ----------------
// grid = B*C*H blocks (one per output row), 256 threads (4 px each, 16B vec I/O) (proven round-0)
__global__ __launch_bounds__(256) void k5_final(
        const float* __restrict__ g,
        const float* __restrict__ ws,
        float* __restrict__ out) {
    int blk = blockIdx.x;
    int y  = blk & 1023;
    int bc = blk >> 10;
    int b = bc / 3, c = bc % 3;
    float fy = (float)y * (30.f / 1023.f);
    int y0 = (int)fy;
    float wy = fy - (float)y0;
    int y1i = min(y0 + 1, 30);
    const float* A0 = ws + OFF_A  + c * NP_ + b * NPOSPB_ + y0  * OH_;
    const float* A1 = ws + OFF_A  + c * NP_ + b * NPOSPB_ + y1i * OH_;
    const float* B0 = ws + OFF_BV + c * NP_ + b * NPOSPB_ + y0  * OH_;
    const float* B1 = ws + OFF_BV + c * NP_ + b * NPOSPB_ + y1i * OH_;
    int t = threadIdx.x;
    size_t rowoff = ((size_t)bc * H_ + (size_t)y) * W_;
    const f4* gp = (const f4*)(g + rowoff);
    f4* op = (f4*)(out + rowoff);
    f4 gv = gp[t];
    float go[4] = { gv.x, gv.y, gv.z, gv.w };
    float r[4];
#pragma unroll
    for (int j = 0; j < 4; j++) {
        int x = t * 4 + j;
        float fx = (float)x * (30.f / 1023.f);
        int x0 = (int)fx;
        float wx = fx - (float)x0;
        int x1 = min(x0 + 1, 30);
        float a  = (A0[x0] * (1.f - wx) + A0[x1] * wx) * (1.f - wy)
                 + (A1[x0] * (1.f - wx) + A1[x1] * wx) * wy;
        float bb = (B0[x0] * (1.f - wx) + B0[x1] * wx) * (1.f - wy)
                 + (B1[x0] * (1.f - wx) + B1[x1] * wx) * wy;
        r[j] = a * go[j] + bb;
    }
    f4 ov;
    ov.x = r[0]; ov.y = r[1]; ov.z = r[2]; ov.w = r[3];
    __builtin_nontemporal_store(ov, op + t);   // out never re-read
}

extern "C" void kernel_launch(void* const* d_in, const int* in_sizes, int n_in,
                              void* d_out, int out_size, void* d_ws, size_t ws_size,
                              hipStream_t stream) {
    const float* guide = (const float*)d_in[0];
    const float* src   = (const float*)d_in[1];
    // d_in[2] = box_w (all ones) -- unused; N == 4096 everywhere (VALID padding)
    const float* w1 = (const float*)d_in[3];
    const float* g1 = (const float*)d_in[4];
    const float* b1 = (const float*)d_in[5];
    const float* w2 = (const float*)d_in[6];
    const float* g2 = (const float*)d_in[7];
    const float* b2 = (const float*)d_in[8];
    const float* w3 = (const float*)d_in[9];
    float* ws = (float*)d_ws;
    float* out = (float*)d_out;

    hipLaunchKernelGGL(k1_tilesums, dim3(B_ * C_ * NHS_), dim3(256), 0, stream, guide, src, ws);
    hipLaunchKernelGGL(kmid,        dim3(1),              dim3(512), 0, stream,
                       w1, g1, b1, w2, g2, b2, w3, ws);
    hipLaunchKernelGGL(k5_final,    dim3(B_ * C_ * H_),   dim3(256), 0, stream, guide, ws, out);
}

// Round 3
// 200.001 us; speedup vs baseline: 2.6597x; 1.5473x over previous
//
#include <hip/hip_runtime.h>
#include <stdint.h>

// Problem constants
#define B_      4
#define C_      3
#define H_      1024
#define W_      1024
#define OH_     31          // (1024-64)/32 + 1
#define NHS_    64          // 16-row half-strips per image
#define NP_     3844        // B * OH * OH
#define NPOSPB_ 961         // OH*OH
#define EPS_    1e-5f

#define NBLK_MID 16

// ---------------- ws layout (float offsets) ----------------
#define TILE_PLANE 24576    // 12 bc * 64 hs * 32 tx
#define OFF_TILE  0         // 4 planes * 24576 = 98304
#define OFF_STATS 98304     // 128 floats: s1 sum[32], s1 sq[32], s2 sum[32], s2 sq[32]
#define OFF_BAR   98432     // 4 ints (barrier counters; zeroed by k1 each launch)
#define OFF_A     98436     // 3 * 3844
#define OFF_BV    109968    // 3 * 3844  (end 121500 floats ~= 486 KB; L2-resident)

typedef float f4 __attribute__((ext_vector_type(4)));

// ---------------- K1: 16-row half-strip partial sums of g, s, g*s, g*g per 32-col tile ----------------
// grid = (B*C)*64 = 768 blocks, 256 threads. (proven round-0; ~HBM floor)
__global__ __launch_bounds__(256) void k1_tilesums(
        const float* __restrict__ g,
        const float* __restrict__ s,
        float* __restrict__ ws) {
    int blk = blockIdx.x;
    int bc = blk >> 6;        // 0..11
    int hs = blk & 63;        // half-strip (16 rows)
    int t  = threadIdx.x;     // covers columns [4t, 4t+4)
    const f4* gp = (const f4*)(g + ((size_t)bc * H_ + (size_t)hs * 16) * W_);
    const f4* sp = (const f4*)(s + ((size_t)bc * H_ + (size_t)hs * 16) * W_);
    float sg = 0.f, ss = 0.f, sgs = 0.f, sgg = 0.f;
#pragma unroll 4
    for (int r = 0; r < 16; r++) {
        f4 gv = gp[r * (W_ / 4) + t];
        f4 sv = __builtin_nontemporal_load(sp + r * (W_ / 4) + t);  // src read exactly once
        sg  += (gv.x + gv.y) + (gv.z + gv.w);
        ss  += (sv.x + sv.y) + (sv.z + sv.w);
        sgs += gv.x * sv.x + gv.y * sv.y + gv.z * sv.z + gv.w * sv.w;
        sgg += gv.x * gv.x + gv.y * gv.y + gv.z * gv.z + gv.w * gv.w;
    }
    // reduce groups of 8 lanes (8 threads * 4 cols = 32 cols = one tileX)
#pragma unroll
    for (int off = 4; off; off >>= 1) {
        sg  += __shfl_down(sg,  off, 8);
        ss  += __shfl_down(ss,  off, 8);
        sgs += __shfl_down(sgs, off, 8);
        sgg += __shfl_down(sgg, off, 8);
    }
    if ((t & 7) == 0) {
        int tx = t >> 3;
        int base = (bc * NHS_ + hs) * 32 + tx;
        ws[OFF_TILE + 0 * TILE_PLANE + base] = sg;
        ws[OFF_TILE + 1 * TILE_PLANE + base] = ss;
        ws[OFF_TILE + 2 * TILE_PLANE + base] = sgs;
        ws[OFF_TILE + 3 * TILE_PLANE + base] = sgg;
    }
    // zero stats accumulators (128) + barrier counters (4) for this launch
    if (blk == 0 && t < 132) ws[OFF_STATS + t] = 0.f;
}

// ---------------- 16-block device barrier (dedicated monotonic counter per use) ----------------
// Safe: 16 blocks are always co-resident on 256 CUs; counters zeroed by k1 (prior
// kernel in stream); atomics are device-scope (cross-XCD coherent point); spin uses
// agent-scope atomic load so no stale L1/L2 copy is observed.
__device__ __forceinline__ void bar16(float* ws, int idx) {
    __syncthreads();
    if (threadIdx.x == 0) {
        __threadfence();
        int* ctr = (int*)(ws + OFF_BAR) + idx;
        __atomic_fetch_add(ctr, 1, __ATOMIC_ACQ_REL);
        while (__hip_atomic_load(ctr, __ATOMIC_ACQUIRE, __HIP_MEMORY_SCOPE_AGENT) < NBLK_MID) {
            __builtin_amdgcn_s_sleep(2);
        }
    }
    __syncthreads();
}

// ============================================================================
// KMID: 16 blocks x 256 threads = 4096 threads, ONE position per thread.
// Fuses conv1 -> BN1 -> conv2 -> BN2 -> conv3. y1/z1/y2/mx/my all stay in
// REGISTERS across the two BN barriers (same thread owns position p
// throughout) — zero intermediate global traffic. BN batch stats via
// wave-shuffle -> LDS -> per-block atomicAdd (16 adds/address), then bar16.
// Weights read with wave-uniform compile-time offsets -> s_load (scalar pipe).
// ============================================================================
__global__ __launch_bounds__(256) void kmid(
        const float* __restrict__ w1f,
        const float* __restrict__ g1f,
        const float* __restrict__ b1f,
        const float* __restrict__ w2f,
        const float* __restrict__ g2f,
        const float* __restrict__ b2f,
        const float* __restrict__ w3f,
        float* __restrict__ ws) {
    __shared__ float red[4][64];
    __shared__ float scs[32], shs[32];
    int t  = threadIdx.x;
    int wv = t >> 6, ln = t & 63;
    int p  = blockIdx.x * 256 + t;
    bool ok = p < NP_;
    int pp = ok ? p : 0;
    int b  = pp / NPOSPB_;
    int r  = pp % NPOSPB_;
    int oy = r / OH_, ox = r % OH_;

    // ---------------- phase A: window sums -> h -> conv1 (regs) ----------------
    float h[6], mxv[3], myv[3];
#pragma unroll
    for (int c = 0; c < 3; c++) {
        int bc = b * 3 + c;
        int base = (bc * NHS_ + oy * 2) * 32 + ox;
        float S[4];
#pragma unroll
        for (int pl = 0; pl < 4; pl++) {
            const float* tp = ws + OFF_TILE + pl * TILE_PLANE + base;
            S[pl] = ((tp[0]  + tp[1])  + (tp[32] + tp[33]))
                  + ((tp[64] + tp[65]) + (tp[96] + tp[97]));
        }
        const float inv = 1.f / 4096.f;
        float mx = S[0] * inv, my = S[1] * inv;
        h[c]     = S[2] * inv - mx * my;
        h[3 + c] = S[3] * inv - mx * mx;
        mxv[c] = mx; myv[c] = my;
    }
    float a[32];
#pragma unroll
    for (int o = 0; o < 32; o++) {
        float y = 0.f;
#pragma unroll
        for (int i = 0; i < 6; i++) y += w1f[o * 6 + i] * h[i];
        a[o] = y;
    }

    // stats1: wave shuffle -> LDS -> block total -> atomicAdd (16 per address)
#pragma unroll
    for (int o = 0; o < 32; o++) {
        float sv = ok ? a[o] : 0.f;
        float sq = sv * sv;
#pragma unroll
        for (int off = 32; off; off >>= 1) {
            sv += __shfl_down(sv, off, 64);
            sq += __shfl_down(sq, off, 64);
        }
        if (ln == 0) { red[wv][o] = sv; red[wv][32 + o] = sq; }
    }
    __syncthreads();
    if (t < 64) {
        float tot = red[0][t] + red[1][t] + red[2][t] + red[3][t];
        atomicAdd(&ws[OFF_STATS + t], tot);
    }
    bar16(ws, 0);

    // BN1 params (agent-scope loads: atomics' home is the coherent point)
    if (t < 32) {
        float sm = __hip_atomic_load(&ws[OFF_STATS + t],      __ATOMIC_RELAXED, __HIP_MEMORY_SCOPE_AGENT);
        float sq = __hip_atomic_load(&ws[OFF_STATS + 32 + t], __ATOMIC_RELAXED, __HIP_MEMORY_SCOPE_AGENT);
        float m = sm * (1.f / NP_);
        float v = sq * (1.f / NP_) - m * m;
        float sc = g1f[t] * rsqrtf(v + EPS_);
        scs[t] = sc; shs[t] = b1f[t] - m * sc;
    }
    __syncthreads();

    // ---------------- phase B: BN1+ReLU -> conv2 (regs) ----------------
#pragma unroll
    for (int i = 0; i < 32; i++) a[i] = fmaxf(a[i] * scs[i] + shs[i], 0.f);
    float y2[32];
#pragma unroll
    for (int o = 0; o < 32; o++) {
        float y = 0.f;
#pragma unroll
        for (int i = 0; i < 32; i++) y += w2f[o * 32 + i] * a[i];   // SGPR operand stream
        y2[o] = y;
    }

    // stats2
#pragma unroll
    for (int o = 0; o < 32; o++) {
        float sv = ok ? y2[o] : 0.f;
        float sq = sv * sv;
#pragma unroll
        for (int off = 32; off; off >>= 1) {
            sv += __shfl_down(sv, off, 64);
            sq += __shfl_down(sq, off, 64);
        }
        if (ln == 0) { red[wv][o] = sv; red[wv][32 + o] = sq; }
    }
    __syncthreads();
    if (t < 64) {
        float tot = red[0][t] + red[1][t] + red[2][t] + red[3][t];
        atomicAdd(&ws[OFF_STATS + 64 + t], tot);
    }
    bar16(ws, 1);

    if (t < 32) {
        float sm = __hip_atomic_load(&ws[OFF_STATS + 64 + t], __ATOMIC_RELAXED, __HIP_MEMORY_SCOPE_AGENT);
        float sq = __hip_atomic_load(&ws[OFF_STATS + 96 + t], __ATOMIC_RELAXED, __HIP_MEMORY_SCOPE_AGENT);
        float m = sm * (1.f / NP_);
        float v = sq * (1.f / NP_) - m * m;
        float sc = g2f[t] * rsqrtf(v + EPS_);
        scs[t] = sc; shs[t] = b2f[t] - m * sc;
    }
    __syncthreads();

    // ---------------- phase C: BN2+ReLU -> conv3 -> A, b ----------------
#pragma unroll
    for (int i = 0; i < 32; i++) y2[i] = fmaxf(y2[i] * scs[i] + shs[i], 0.f);
    if (ok) {
#pragma unroll
        for (int c = 0; c < 3; c++) {
            float av = 0.f;
#pragma unroll
            for (int i = 0; i < 32; i++) av += w3f[c * 32 + i] * y2[i];
            ws[OFF_A  + c * NP_ + p] = av;
            ws[OFF_BV + c * NP_ + p] = myv[c] - av * mxv[c];
        }
    }
}

// ---------------- K5: bilinear upsample (align_corners) + out = A*g + b ----------------
// grid = B*C*H blocks (one per output row), 256 threads (4 px each, 16B vec I/O) (proven round-0)
__global__ __launch_bounds__(256) void k5_final(
        const float* __restrict__ g,
        const float* __restrict__ ws,
        float* __restrict__ out) {
    int blk = blockIdx.x;
    int y  = blk & 1023;
    int bc = blk >> 10;
    int b = bc / 3, c = bc % 3;
    float fy = (float)y * (30.f / 1023.f);
    int y0 = (int)fy;
    float wy = fy - (float)y0;
    int y1i = min(y0 + 1, 30);
    const float* A0 = ws + OFF_A  + c * NP_ + b * NPOSPB_ + y0  * OH_;
    const float* A1 = ws + OFF_A  + c * NP_ + b * NPOSPB_ + y1i * OH_;
    const float* B0 = ws + OFF_BV + c * NP_ + b * NPOSPB_ + y0  * OH_;
    const float* B1 = ws + OFF_BV + c * NP_ + b * NPOSPB_ + y1i * OH_;
    int t = threadIdx.x;
    size_t rowoff = ((size_t)bc * H_ + (size_t)y) * W_;
    const f4* gp = (const f4*)(g + rowoff);
    f4* op = (f4*)(out + rowoff);
    f4 gv = gp[t];
    float go[4] = { gv.x, gv.y, gv.z, gv.w };
    float r[4];
#pragma unroll
    for (int j = 0; j < 4; j++) {
        int x = t * 4 + j;
        float fx = (float)x * (30.f / 1023.f);
        int x0 = (int)fx;
        float wx = fx - (float)x0;
        int x1 = min(x0 + 1, 30);
        float a  = (A0[x0] * (1.f - wx) + A0[x1] * wx) * (1.f - wy)
                 + (A1[x0] * (1.f - wx) + A1[x1] * wx) * wy;
        float bb = (B0[x0] * (1.f - wx) + B0[x1] * wx) * (1.f - wy)
                 + (B1[x0] * (1.f - wx) + B1[x1] * wx) * wy;
        r[j] = a * go[j] + bb;
    }
    f4 ov;
    ov.x = r[0]; ov.y = r[1]; ov.z = r[2]; ov.w = r[3];
    __builtin_nontemporal_store(ov, op + t);   // out never re-read
}

extern "C" void kernel_launch(void* const* d_in, const int* in_sizes, int n_in,
                              void* d_out, int out_size, void* d_ws, size_t ws_size,
                              hipStream_t stream) {
    const float* guide = (const float*)d_in[0];
    const float* src   = (const float*)d_in[1];
    // d_in[2] = box_w (all ones) -- unused; N == 4096 everywhere (VALID padding)
    const float* w1 = (const float*)d_in[3];
    const float* g1 = (const float*)d_in[4];
    const float* b1 = (const float*)d_in[5];
    const float* w2 = (const float*)d_in[6];
    const float* g2 = (const float*)d_in[7];
    const float* b2 = (const float*)d_in[8];
    const float* w3 = (const float*)d_in[9];
    float* ws = (float*)d_ws;
    float* out = (float*)d_out;

    hipLaunchKernelGGL(k1_tilesums, dim3(B_ * C_ * NHS_), dim3(256), 0, stream, guide, src, ws);
    hipLaunchKernelGGL(kmid,        dim3(NBLK_MID),       dim3(256), 0, stream,
                       w1, g1, b1, w2, g2, b2, w3, ws);
    hipLaunchKernelGGL(k5_final,    dim3(B_ * C_ * H_),   dim3(256), 0, stream, guide, ws, out);
}

// Round 4
// 181.761 us; speedup vs baseline: 2.9266x; 1.1003x over previous
//
#include <hip/hip_runtime.h>
#include <stdint.h>

// Problem constants
#define B_      4
#define C_      3
#define H_      1024
#define W_      1024
#define OH_     31          // (1024-64)/32 + 1
#define NHS_    64          // 16-row half-strips per image
#define NP_     3844        // B * OH * OH
#define NPOSPB_ 961         // OH*OH
#define EPS_    1e-5f

#define NBLK_MID 16

// ---------------- ws layout (float offsets) ----------------
#define TILE_PLANE 24576    // 12 bc * 64 hs * 32 tx
#define OFF_TILE  0         // 4 planes * 24576 = 98304
#define OFF_STATS 98304     // 128 floats: s1 sum[32], s1 sq[32], s2 sum[32], s2 sq[32]
#define OFF_BAR   98432     // 4 ints (barrier counters; zeroed by k1 each launch)
#define OFF_A     98436     // 3 * 3844
#define OFF_BV    109968    // 3 * 3844  (end 121500 floats ~= 486 KB; L2/L3-resident)

typedef float f4 __attribute__((ext_vector_type(4)));

// ---------------- K1: 16-row half-strip partial sums of g, s, g*s, g*g per 32-col tile ----------------
// grid = (B*C)*64 = 768 blocks, 256 threads. (proven; ~HBM floor)
__global__ __launch_bounds__(256) void k1_tilesums(
        const float* __restrict__ g,
        const float* __restrict__ s,
        float* __restrict__ ws) {
    int blk = blockIdx.x;
    int bc = blk >> 6;        // 0..11
    int hs = blk & 63;        // half-strip (16 rows)
    int t  = threadIdx.x;     // covers columns [4t, 4t+4)
    const f4* gp = (const f4*)(g + ((size_t)bc * H_ + (size_t)hs * 16) * W_);
    const f4* sp = (const f4*)(s + ((size_t)bc * H_ + (size_t)hs * 16) * W_);
    float sg = 0.f, ss = 0.f, sgs = 0.f, sgg = 0.f;
#pragma unroll 4
    for (int r = 0; r < 16; r++) {
        f4 gv = gp[r * (W_ / 4) + t];
        f4 sv = __builtin_nontemporal_load(sp + r * (W_ / 4) + t);  // src read exactly once
        sg  += (gv.x + gv.y) + (gv.z + gv.w);
        ss  += (sv.x + sv.y) + (sv.z + sv.w);
        sgs += gv.x * sv.x + gv.y * sv.y + gv.z * sv.z + gv.w * sv.w;
        sgg += gv.x * gv.x + gv.y * gv.y + gv.z * gv.z + gv.w * gv.w;
    }
    // reduce groups of 8 lanes (8 threads * 4 cols = 32 cols = one tileX)
#pragma unroll
    for (int off = 4; off; off >>= 1) {
        sg  += __shfl_down(sg,  off, 8);
        ss  += __shfl_down(ss,  off, 8);
        sgs += __shfl_down(sgs, off, 8);
        sgg += __shfl_down(sgg, off, 8);
    }
    if ((t & 7) == 0) {
        int tx = t >> 3;
        int base = (bc * NHS_ + hs) * 32 + tx;
        ws[OFF_TILE + 0 * TILE_PLANE + base] = sg;
        ws[OFF_TILE + 1 * TILE_PLANE + base] = ss;
        ws[OFF_TILE + 2 * TILE_PLANE + base] = sgs;
        ws[OFF_TILE + 3 * TILE_PLANE + base] = sgg;
    }
    // zero stats accumulators (128) + barrier counters (4) for this launch
    if (blk == 0 && t < 132) ws[OFF_STATS + t] = 0.f;
}

// ---------------- 16-block device barrier (dedicated monotonic counter per use) ----------------
// Safe: 16 blocks always co-resident; counters zeroed by k1 (prior kernel in stream);
// arrive = device-scope atomicAdd (coherent point); spin = agent-scope acquire load.
__device__ __forceinline__ void bar16(float* ws, int idx) {
    __syncthreads();
    if (threadIdx.x == 0) {
        __threadfence();
        int* ctr = (int*)(ws + OFF_BAR) + idx;
        __atomic_fetch_add(ctr, 1, __ATOMIC_ACQ_REL);
        while (__hip_atomic_load(ctr, __ATOMIC_ACQUIRE, __HIP_MEMORY_SCOPE_AGENT) < NBLK_MID) {
            __builtin_amdgcn_s_sleep(1);
        }
    }
    __syncthreads();
}

// ============================================================================
// KMID: 16 blocks x 1024 threads. Each position p is handled by FOUR waves
// (channel groups of 8): wave w -> group k = w&3, positions blk*256 + (w>>2)*64 + lane.
// Per-thread work drops 4x (conv2: 256 FMA) and each CU runs 16 waves (4/SIMD)
// for latency hiding — round-3's kmid was 1 wave/SIMD and purely chain-bound.
// z vectors cross channel groups via stride-33 LDS (conflict-free: (33p+i)&31
// = (p+i)&31). Channel-group base is readfirstlane'd so weight addresses are
// wave-uniform -> s_load on the scalar pipe. 2 cross-block barriers (BN1, BN2).
// ============================================================================
__global__ __launch_bounds__(1024) void kmid(
        const float* __restrict__ w1f,
        const float* __restrict__ g1f,
        const float* __restrict__ b1f,
        const float* __restrict__ w2f,
        const float* __restrict__ g2f,
        const float* __restrict__ b2f,
        const float* __restrict__ w3f,
        float* __restrict__ ws) {
    __shared__ float zbuf[256 * 33];     // [pos_local][ch] padded stride 33
    __shared__ float red[16][16];        // per-wave partials: [wave][j] sum, [wave][8+j] sq
    __shared__ float scs[32], shs[32];
    int t    = threadIdx.x;
    int w    = t >> 6;
    int lane = t & 63;
    int k    = w & 3;                                    // channel group 0..3
    int ko8  = __builtin_amdgcn_readfirstlane(k * 8);    // force SGPR: wave-uniform weight base
    int pl   = (w >> 2) * 64 + lane;                     // local position 0..255
    int p    = blockIdx.x * 256 + pl;
    bool ok  = p < NP_;
    int pp   = ok ? p : 0;
    int b    = pp / NPOSPB_;
    int r    = pp % NPOSPB_;
    int oy   = r / OH_, ox = r % OH_;

    // ---------------- phase A: window sums -> h -> conv1 (my 8 channels) ----------------
    float h[6], mxv[3], myv[3];
#pragma unroll
    for (int c = 0; c < 3; c++) {
        int bc = b * 3 + c;
        int base = (bc * NHS_ + oy * 2) * 32 + ox;
        float S[4];
#pragma unroll
        for (int plane = 0; plane < 4; plane++) {
            const float* tp = ws + OFF_TILE + plane * TILE_PLANE + base;
            S[plane] = ((tp[0]  + tp[1])  + (tp[32] + tp[33]))
                     + ((tp[64] + tp[65]) + (tp[96] + tp[97]));
        }
        const float inv = 1.f / 4096.f;
        float mx = S[0] * inv, my = S[1] * inv;
        h[c]     = S[2] * inv - mx * my;
        h[3 + c] = S[3] * inv - mx * mx;
        mxv[c] = mx; myv[c] = my;
    }
    float a[8];
#pragma unroll
    for (int j = 0; j < 8; j++) {
        float y = 0.f;
#pragma unroll
        for (int i = 0; i < 6; i++) y += w1f[(ko8 + j) * 6 + i] * h[i];   // s_load
        a[j] = y;
    }

    // stats1: per-wave shuffle reduce (8 ch) -> LDS -> cross-wave -> atomicAdd
    {
        float sv[8], sq[8];
#pragma unroll
        for (int j = 0; j < 8; j++) { sv[j] = ok ? a[j] : 0.f; sq[j] = sv[j] * sv[j]; }
#pragma unroll
        for (int off = 32; off; off >>= 1) {
#pragma unroll
            for (int j = 0; j < 8; j++) {
                sv[j] += __shfl_down(sv[j], off, 64);
                sq[j] += __shfl_down(sq[j], off, 64);
            }
        }
        if (lane == 0) {
#pragma unroll
            for (int j = 0; j < 8; j++) { red[w][j] = sv[j]; red[w][8 + j] = sq[j]; }
        }
    }
    __syncthreads();
    if (t < 64) {
        int o = t & 31; int kk = o >> 3; int col = ((t >= 32) ? 8 : 0) + (o & 7);
        float tot = red[kk][col] + red[kk + 4][col] + red[kk + 8][col] + red[kk + 12][col];
        atomicAdd(&ws[OFF_STATS + ((t >= 32) ? 32 : 0) + o], tot);
    }
    bar16(ws, 0);

    // BN1 params (agent-scope loads: atomics' home is the coherent point)
    if (t < 32) {
        float sm = __hip_atomic_load(&ws[OFF_STATS + t],      __ATOMIC_RELAXED, __HIP_MEMORY_SCOPE_AGENT);
        float sq = __hip_atomic_load(&ws[OFF_STATS + 32 + t], __ATOMIC_RELAXED, __HIP_MEMORY_SCOPE_AGENT);
        float m = sm * (1.f / NP_);
        float v = sq * (1.f / NP_) - m * m;
        float sc = g1f[t] * rsqrtf(v + EPS_);
        scs[t] = sc; shs[t] = b1f[t] - m * sc;
    }
    __syncthreads();

    // ---------------- phase B: BN1+ReLU -> z to LDS -> conv2 (my 8 channels) ----------------
#pragma unroll
    for (int j = 0; j < 8; j++) {
        float zz = fmaxf(a[j] * scs[ko8 + j] + shs[ko8 + j], 0.f);
        zbuf[pl * 33 + ko8 + j] = zz;
    }
    __syncthreads();
    float zal[32];
#pragma unroll
    for (int i = 0; i < 32; i++) zal[i] = zbuf[pl * 33 + i];   // conflict-free
    float y2[8];
#pragma unroll
    for (int j = 0; j < 8; j++) {
        float y = 0.f;
#pragma unroll
        for (int i = 0; i < 32; i++) y += w2f[(ko8 + j) * 32 + i] * zal[i];   // s_load stream
        y2[j] = y;
    }

    // stats2
    {
        float sv[8], sq[8];
#pragma unroll
        for (int j = 0; j < 8; j++) { sv[j] = ok ? y2[j] : 0.f; sq[j] = sv[j] * sv[j]; }
#pragma unroll
        for (int off = 32; off; off >>= 1) {
#pragma unroll
            for (int j = 0; j < 8; j++) {
                sv[j] += __shfl_down(sv[j], off, 64);
                sq[j] += __shfl_down(sq[j], off, 64);
            }
        }
        if (lane == 0) {
#pragma unroll
            for (int j = 0; j < 8; j++) { red[w][j] = sv[j]; red[w][8 + j] = sq[j]; }
        }
    }
    __syncthreads();
    if (t < 64) {
        int o = t & 31; int kk = o >> 3; int col = ((t >= 32) ? 8 : 0) + (o & 7);
        float tot = red[kk][col] + red[kk + 4][col] + red[kk + 8][col] + red[kk + 12][col];
        atomicAdd(&ws[OFF_STATS + 64 + ((t >= 32) ? 32 : 0) + o], tot);
    }
    bar16(ws, 1);

    if (t < 32) {
        float sm = __hip_atomic_load(&ws[OFF_STATS + 64 + t], __ATOMIC_RELAXED, __HIP_MEMORY_SCOPE_AGENT);
        float sq = __hip_atomic_load(&ws[OFF_STATS + 96 + t], __ATOMIC_RELAXED, __HIP_MEMORY_SCOPE_AGENT);
        float m = sm * (1.f / NP_);
        float v = sq * (1.f / NP_) - m * m;
        float sc = g2f[t] * rsqrtf(v + EPS_);
        scs[t] = sc; shs[t] = b2f[t] - m * sc;
    }
    __syncthreads();

    // ---------------- phase C: BN2+ReLU -> z2 to LDS -> conv3 (group-0 waves) ----------------
#pragma unroll
    for (int j = 0; j < 8; j++) {
        float zz = fmaxf(y2[j] * scs[ko8 + j] + shs[ko8 + j], 0.f);
        zbuf[pl * 33 + ko8 + j] = zz;     // safe: all conv2-era reads completed before bar16(1)
    }
    __syncthreads();
    if (k == 0 && ok) {
        float z2[32];
#pragma unroll
        for (int i = 0; i < 32; i++) z2[i] = zbuf[pl * 33 + i];
#pragma unroll
        for (int c = 0; c < 3; c++) {
            float av = 0.f;
#pragma unroll
            for (int i = 0; i < 32; i++) av += w3f[c * 32 + i] * z2[i];   // s_load
            ws[OFF_A  + c * NP_ + p] = av;
            ws[OFF_BV + c * NP_ + p] = myv[c] - av * mxv[c];
        }
    }
}

// ---------------- K5: bilinear upsample (align_corners) + out = A*g + b ----------------
// grid = B*C*H blocks (one per output row), 256 threads (4 px each, 16B vec I/O) (proven)
__global__ __launch_bounds__(256) void k5_final(
        const float* __restrict__ g,
        const float* __restrict__ ws,
        float* __restrict__ out) {
    int blk = blockIdx.x;
    int y  = blk & 1023;
    int bc = blk >> 10;
    int b = bc / 3, c = bc % 3;
    float fy = (float)y * (30.f / 1023.f);
    int y0 = (int)fy;
    float wy = fy - (float)y0;
    int y1i = min(y0 + 1, 30);
    const float* A0 = ws + OFF_A  + c * NP_ + b * NPOSPB_ + y0  * OH_;
    const float* A1 = ws + OFF_A  + c * NP_ + b * NPOSPB_ + y1i * OH_;
    const float* B0 = ws + OFF_BV + c * NP_ + b * NPOSPB_ + y0  * OH_;
    const float* B1 = ws + OFF_BV + c * NP_ + b * NPOSPB_ + y1i * OH_;
    int t = threadIdx.x;
    size_t rowoff = ((size_t)bc * H_ + (size_t)y) * W_;
    const f4* gp = (const f4*)(g + rowoff);
    f4* op = (f4*)(out + rowoff);
    f4 gv = gp[t];
    float go[4] = { gv.x, gv.y, gv.z, gv.w };
    float r[4];
#pragma unroll
    for (int j = 0; j < 4; j++) {
        int x = t * 4 + j;
        float fx = (float)x * (30.f / 1023.f);
        int x0 = (int)fx;
        float wx = fx - (float)x0;
        int x1 = min(x0 + 1, 30);
        float a  = (A0[x0] * (1.f - wx) + A0[x1] * wx) * (1.f - wy)
                 + (A1[x0] * (1.f - wx) + A1[x1] * wx) * wy;
        float bb = (B0[x0] * (1.f - wx) + B0[x1] * wx) * (1.f - wy)
                 + (B1[x0] * (1.f - wx) + B1[x1] * wx) * wy;
        r[j] = a * go[j] + bb;
    }
    f4 ov;
    ov.x = r[0]; ov.y = r[1]; ov.z = r[2]; ov.w = r[3];
    __builtin_nontemporal_store(ov, op + t);   // out never re-read
}

extern "C" void kernel_launch(void* const* d_in, const int* in_sizes, int n_in,
                              void* d_out, int out_size, void* d_ws, size_t ws_size,
                              hipStream_t stream) {
    const float* guide = (const float*)d_in[0];
    const float* src   = (const float*)d_in[1];
    // d_in[2] = box_w (all ones) -- unused; N == 4096 everywhere (VALID padding)
    const float* w1 = (const float*)d_in[3];
    const float* g1 = (const float*)d_in[4];
    const float* b1 = (const float*)d_in[5];
    const float* w2 = (const float*)d_in[6];
    const float* g2 = (const float*)d_in[7];
    const float* b2 = (const float*)d_in[8];
    const float* w3 = (const float*)d_in[9];
    float* ws = (float*)d_ws;
    float* out = (float*)d_out;

    hipLaunchKernelGGL(k1_tilesums, dim3(B_ * C_ * NHS_), dim3(256),  0, stream, guide, src, ws);
    hipLaunchKernelGGL(kmid,        dim3(NBLK_MID),       dim3(1024), 0, stream,
                       w1, g1, b1, w2, g2, b2, w3, ws);
    hipLaunchKernelGGL(k5_final,    dim3(B_ * C_ * H_),   dim3(256),  0, stream, guide, ws, out);
}